// Round 3
// baseline (165.542 us; speedup 1.0000x reference)
//
#include <hip/hip_runtime.h>
#include <math.h>

#define N_TOK 8192
#define DIM   2048
#define NE    64
#define TOPK  4
#define THETA 2e-3f
#define TPB2  16                      /* tokens per k_main block */
#define NBLK  (N_TOK / TPB2)          /* 512 */

typedef short bf16x8 __attribute__((ext_vector_type(8)));
typedef float f32x4  __attribute__((ext_vector_type(4)));

// ---- workspace layout (float offsets) ----
#define OFF_LOGITS 0                          /* N_TOK*NE = 524288 */
#define OFF_MAXV   (OFF_LOGITS + N_TOK * NE)  /* 8192 */
#define OFF_DENOM  (OFF_MAXV + N_TOK)
#define OFF_W1     (OFF_DENOM + N_TOK)
#define OFF_C1     (OFF_W1 + N_TOK)           /* int */
#define OFF_NFLAG  (OFF_C1 + N_TOK)           /* int (padded 64) */
#define OFF_FLAGL  (OFF_NFLAG + 64)           /* int, N_TOK */
#define OFF_WH     (OFF_FLAGL + N_TOK)        /* NE*DIM bf16 = 65536 floats */
#define OFF_WL     (OFF_WH + NE * DIM / 2)
#define OFF_WTMP   (OFF_WL + NE * DIM / 2)    /* N_TOK*TOPK */

// pack 2 fp32 -> 2 truncated bf16 (hi) and 2 truncated bf16 of residual (lo)
__device__ inline void cvt2(float a, float b, unsigned& hi, unsigned& lo) {
    const unsigned ua = __float_as_uint(a), ub = __float_as_uint(b);
    hi = __builtin_amdgcn_perm(ub, ua, 0x07060302u);   // [a_hi16, b_hi16]
    const float ra = a - __uint_as_float(ua & 0xFFFF0000u);
    const float rb = b - __uint_as_float(ub & 0xFFFF0000u);
    lo = __builtin_amdgcn_perm(__float_as_uint(rb), __float_as_uint(ra), 0x07060302u);
}

union FragU { unsigned u[4]; bf16x8 v; uint4 q; };

__device__ inline void make_frags(const float4& p, const float4& q,
                                  bf16x8& hi, bf16x8& lo) {
    FragU H, L;
    cvt2(p.x, p.y, H.u[0], L.u[0]);
    cvt2(p.z, p.w, H.u[1], L.u[1]);
    cvt2(q.x, q.y, H.u[2], L.u[2]);
    cvt2(q.z, q.w, H.u[3], L.u[3]);
    hi = H.v; lo = L.v;
}

// W (64x2048 fp32) -> wh/wl truncated-bf16 pair arrays (row-major, k-linear)
__global__ __launch_bounds__(256)
void k_wc(const float* __restrict__ W, unsigned short* __restrict__ wh,
          unsigned short* __restrict__ wl) {
    const int i = (blockIdx.x * 256 + threadIdx.x) * 8;
    const float4 p = *reinterpret_cast<const float4*>(W + i);
    const float4 q = *reinterpret_cast<const float4*>(W + i + 4);
    FragU H, L;
    cvt2(p.x, p.y, H.u[0], L.u[0]);
    cvt2(p.z, p.w, H.u[1], L.u[1]);
    cvt2(q.x, q.y, H.u[2], L.u[2]);
    cvt2(q.z, q.w, H.u[3], L.u[3]);
    *reinterpret_cast<uint4*>(wh + i) = H.q;
    *reinterpret_cast<uint4*>(wl + i) = L.q;
}

// Fused split-bf16 MFMA GEMM + per-token stats.
// Block: 512 thr (8 waves), 16 tokens, full K (wave w owns k-chunk [w*256, w*256+256)).
// Wave tile: 16 tokens x 64 experts via 4 N-tiles of 16x16x32 MFMA, 4 products
// (xh*wh + xh*wl + xl*wh + xl*wl). A/B use identical (lane-group,elem)->k maps,
// so the physical k permutation cancels. C/D: col(expert)=lane&15,
// row(token)=(lane>>4)*4+reg [m89-verified].
__global__ __launch_bounds__(512, 4)
void k_main(const float* __restrict__ x, const unsigned short* __restrict__ wh,
            const unsigned short* __restrict__ wl, const float* __restrict__ bias,
            float* __restrict__ logits, float* __restrict__ maxv,
            float* __restrict__ denomv, float* __restrict__ w1f,
            int* __restrict__ c1, int* __restrict__ nflag, int* __restrict__ flagl) {
    __shared__ float red[8][TPB2][68];   // 34816 B, stride 68 -> 2-way (free)
    __shared__ float lbuf[TPB2][68];     //  4352 B

    const int tid = threadIdx.x;
    const int w   = tid >> 6;            // wave 0..7
    const int l   = tid & 63;
    const int t0  = blockIdx.x * TPB2;
    const int m   = l & 15;              // A row (token) / B col (expert low)
    const int g   = l >> 4;              // k-octet group 0..3
    const int kb  = w * (DIM / 8);       // 256 k per wave

    const float* xp = x + (size_t)(t0 + m) * DIM + kb + g * 8;
    const unsigned short* whp = wh + (size_t)m * DIM + kb + g * 8;
    const unsigned short* wlp = wl + (size_t)m * DIM + kb + g * 8;

    f32x4 acc[4];
    #pragma unroll
    for (int nt = 0; nt < 4; ++nt)
        #pragma unroll
        for (int r = 0; r < 4; ++r) acc[nt][r] = 0.0f;

    #pragma unroll 2
    for (int step = 0; step < 8; ++step) {
        const float4 p = *reinterpret_cast<const float4*>(xp + step * 32);
        const float4 q = *reinterpret_cast<const float4*>(xp + step * 32 + 4);
        bf16x8 ah, al;
        make_frags(p, q, ah, al);
        #pragma unroll
        for (int nt = 0; nt < 4; ++nt) {
            FragU bh, bl;
            bh.q = *reinterpret_cast<const uint4*>(whp + (size_t)nt * 16 * DIM + step * 32);
            bl.q = *reinterpret_cast<const uint4*>(wlp + (size_t)nt * 16 * DIM + step * 32);
            acc[nt] = __builtin_amdgcn_mfma_f32_16x16x32_bf16(ah, bh.v, acc[nt], 0, 0, 0);
            acc[nt] = __builtin_amdgcn_mfma_f32_16x16x32_bf16(ah, bl.v, acc[nt], 0, 0, 0);
            acc[nt] = __builtin_amdgcn_mfma_f32_16x16x32_bf16(al, bh.v, acc[nt], 0, 0, 0);
            acc[nt] = __builtin_amdgcn_mfma_f32_16x16x32_bf16(al, bl.v, acc[nt], 0, 0, 0);
        }
    }

    // stash per-wave partial tiles
    #pragma unroll
    for (int nt = 0; nt < 4; ++nt)
        #pragma unroll
        for (int r = 0; r < 4; ++r)
            red[w][g * 4 + r][nt * 16 + m] = acc[nt][r];
    __syncthreads();

    // reduce 8 wave-partials in fixed order, + bias; write logits
    for (int e2 = tid; e2 < TPB2 * NE; e2 += 512) {
        const int t = e2 >> 6, e = e2 & 63;
        float s = red[0][t][e];
        #pragma unroll
        for (int ww = 1; ww < 8; ++ww) s += red[ww][t][e];
        s += bias[e];
        logits[(size_t)(t0 + t) * NE + e] = s;
        lbuf[t][e] = s;
    }
    __syncthreads();

    // stats: wave w handles tokens 2w, 2w+1; lane = expert
    #pragma unroll
    for (int tt = 0; tt < 2; ++tt) {
        const int t = w * 2 + tt;
        const float lv = lbuf[t][l];
        float v1 = lv; int i1 = l; float v2 = -INFINITY;
        #pragma unroll
        for (int off = 32; off; off >>= 1) {
            const float ov1 = __shfl_xor(v1, off);
            const int   oi1 = __shfl_xor(i1, off);
            const float ov2 = __shfl_xor(v2, off);
            if (ov1 > v1 || (ov1 == v1 && oi1 < i1)) {
                v2 = fmaxf(v1, ov2); v1 = ov1; i1 = oi1;
            } else {
                v2 = fmaxf(v2, ov1);
            }
        }
        float s = expf(lv - v1);
        #pragma unroll
        for (int off = 32; off; off >>= 1) s += __shfl_xor(s, off);
        if (l == 0) {
            const int row = t0 + t;
            maxv[row]   = v1;
            denomv[row] = s;
            c1[row]     = i1;
            w1f[row]    = 1.0f / s;
            if (v1 - v2 < THETA) {
                const int ix = atomicAdd(nflag, 1);
                flagl[ix] = row;
            }
        }
    }
}

// Exact fp32 recompute for gap-flagged tokens; bit-reproduces round-2 order
// (per-split sequential-k fmaf, then bias + split0..3).
__global__ __launch_bounds__(256)
void k_exact(const int* __restrict__ nflag, const int* __restrict__ flagl,
             const float* __restrict__ x, const float* __restrict__ W,
             const float* __restrict__ bias, float* __restrict__ logits,
             float* __restrict__ maxv, float* __restrict__ denomv,
             float* __restrict__ w1f, int* __restrict__ c1) {
    __shared__ float part[4][68];
    const int n   = nflag[0];
    const int tid = threadIdx.x;
    const int w   = tid >> 6, l = tid & 63;
    for (int i = blockIdx.x; i < n; i += 64) {
        const int t = flagl[i];
        const float* xr = x + (size_t)t * DIM + w * 512;
        const float* wr = W + (size_t)l * DIM + w * 512;
        float a = 0.0f;
        for (int k = 0; k < 512; k += 4) {
            const float4 xv = *reinterpret_cast<const float4*>(xr + k);
            const float4 wv = *reinterpret_cast<const float4*>(wr + k);
            a = fmaf(xv.x, wv.x, a); a = fmaf(xv.y, wv.y, a);
            a = fmaf(xv.z, wv.z, a); a = fmaf(xv.w, wv.w, a);
        }
        part[w][l] = a;
        __syncthreads();
        if (w == 0) {
            float lg = bias[l];
            #pragma unroll
            for (int s = 0; s < 4; ++s) lg += part[s][l];
            logits[(size_t)t * NE + l] = lg;
            float v = lg; int idx = l;
            #pragma unroll
            for (int off = 32; off; off >>= 1) {
                const float ov = __shfl_xor(v, off);
                const int   oi = __shfl_xor(idx, off);
                if (ov > v || (ov == v && oi < idx)) { v = ov; idx = oi; }
            }
            float p = expf(lg - v);
            #pragma unroll
            for (int off = 32; off; off >>= 1) p += __shfl_xor(p, off);
            if (l == 0) {
                maxv[t]   = v;
                denomv[t] = p;
                c1[t]     = idx;
                w1f[t]    = 1.0f / p;
            }
        }
        __syncthreads();
    }
}

// histogram -> capacity flag -> fast write or exact serial fallback
__global__ __launch_bounds__(256)
void k_decide(const int* __restrict__ c1, const float* __restrict__ w1,
              const float* __restrict__ logits, const float* __restrict__ maxv,
              const float* __restrict__ denomv, const int* __restrict__ tc,
              float* __restrict__ out, float* __restrict__ wtmp) {
    __shared__ int hist[NE];
    __shared__ int flagS;
    const int tid = threadIdx.x;
    if (tid < NE) hist[tid] = 0;
    __syncthreads();
    for (int i = tid; i < N_TOK; i += 256) atomicAdd(&hist[c1[i]], 1);
    __syncthreads();
    const int cap = tc[0] / TOPK;
    if (tid < NE) {
        const bool bad = (TOPK * hist[tid] > cap);
        const unsigned long long mm = __ballot(bad);
        if (tid == 0) flagS = (mm == 0ull) ? 1 : 0;
    }
    __syncthreads();

    if (flagS) {
        const int b = blockIdx.x * 256 + tid;
        const float se = (float)c1[b];
        const float wv = w1[b];
        const float wn = wv / (4.0f * wv + 1e-8f);
        *reinterpret_cast<float4*>(out + (size_t)b * 4) = make_float4(se, se, se, se);
        *reinterpret_cast<float4*>(out + (size_t)N_TOK * TOPK + (size_t)b * 4) =
            make_float4(wn, wn, wn, wn);
        return;
    }

    if (blockIdx.x != 0) return;
    if (tid < 64) {
        const int e = tid;
        int rem = cap;
        for (int k = 0; k < TOPK; ++k) {
            for (int b = 0; b < N_TOK; ++b) {
                const float lg = logits[(size_t)b * NE + e];
                float v = (rem > 0) ? lg : -INFINITY;
                int idx = e;
                #pragma unroll
                for (int off = 32; off; off >>= 1) {
                    const float ov = __shfl_xor(v, off);
                    const int   oi = __shfl_xor(idx, off);
                    if (ov > v || (ov == v && oi < idx)) { v = ov; idx = oi; }
                }
                const bool ok = (v != -INFINITY);
                if (ok && e == idx) rem -= 1;
                const float lc = __shfl(lg, idx);
                if (e == 0) {
                    out[(size_t)b * TOPK + k]  = ok ? (float)idx : -1.0f;
                    wtmp[(size_t)b * TOPK + k] = ok ? expf(lc - maxv[b]) / denomv[b] : 0.0f;
                }
            }
        }
    }
    __syncthreads();
    for (int b = tid; b < N_TOK; b += 256) {
        const float w0 = wtmp[b * 4 + 0], w1_ = wtmp[b * 4 + 1];
        const float w2 = wtmp[b * 4 + 2], w3 = wtmp[b * 4 + 3];
        const float s = ((w0 + w1_) + w2) + w3 + 1e-8f;
        out[N_TOK * TOPK + b * 4 + 0] = w0 / s;
        out[N_TOK * TOPK + b * 4 + 1] = w1_ / s;
        out[N_TOK * TOPK + b * 4 + 2] = w2 / s;
        out[N_TOK * TOPK + b * 4 + 3] = w3 / s;
    }
}

extern "C" void kernel_launch(void* const* d_in, const int* in_sizes, int n_in,
                              void* d_out, int out_size, void* d_ws, size_t ws_size,
                              hipStream_t stream) {
    const float* x    = (const float*)d_in[0];
    const float* W    = (const float*)d_in[1];
    const float* bias = (const float*)d_in[2];
    const int*   tc   = (const int*)d_in[3];

    float* ws       = (float*)d_ws;
    float* logits   = ws + OFF_LOGITS;
    float* maxv     = ws + OFF_MAXV;
    float* denomv   = ws + OFF_DENOM;
    float* w1f      = ws + OFF_W1;
    int*   c1       = (int*)(ws + OFF_C1);
    int*   nflag    = (int*)(ws + OFF_NFLAG);
    int*   flagl    = (int*)(ws + OFF_FLAGL);
    unsigned short* wh = (unsigned short*)(ws + OFF_WH);
    unsigned short* wl = (unsigned short*)(ws + OFF_WL);
    float* wtmp     = ws + OFF_WTMP;
    float* out      = (float*)d_out;

    hipMemsetAsync(nflag, 0, sizeof(int), stream);

    k_wc<<<NE * DIM / 8 / 256, 256, 0, stream>>>(W, wh, wl);
    k_main<<<NBLK, 512, 0, stream>>>(x, wh, wl, bias, logits, maxv, denomv,
                                     w1f, c1, nflag, flagl);
    k_exact<<<64, 256, 0, stream>>>(nflag, flagl, x, W, bias, logits,
                                    maxv, denomv, w1f, c1);
    k_decide<<<N_TOK / 256, 256, 0, stream>>>(c1, w1f, logits, maxv, denomv,
                                              tc, out, wtmp);
}

// Round 4
// 154.954 us; speedup vs baseline: 1.0683x; 1.0683x over previous
//
#include <hip/hip_runtime.h>
#include <math.h>

#define N_TOK 8192
#define DIM   2048
#define NE    64
#define TOPK  4
#define THETA 2e-3f
#define TPB2  16                      /* tokens per k_main block */
#define NBLK  (N_TOK / TPB2)          /* 512 */

typedef short bf16x8 __attribute__((ext_vector_type(8)));
typedef float f32x4  __attribute__((ext_vector_type(4)));

// ---- workspace layout (float offsets) ----
#define OFF_LOGITS 0                          /* N_TOK*NE = 524288 */
#define OFF_MAXV   (OFF_LOGITS + N_TOK * NE)
#define OFF_DENOM  (OFF_MAXV + N_TOK)
#define OFF_W1     (OFF_DENOM + N_TOK)
#define OFF_C1     (OFF_W1 + N_TOK)           /* int */
#define OFF_NFLAG  (OFF_C1 + N_TOK)           /* int (padded 64) */
#define OFF_FLAGL  (OFF_NFLAG + 64)           /* int, N_TOK */
#define OFF_WH     (OFF_FLAGL + N_TOK)        /* NE*DIM bf16 = 65536 floats */
#define OFF_WL     (OFF_WH + NE * DIM / 2)
#define OFF_WT     (OFF_WL + NE * DIM / 2)    /* NE*DIM fp32 transposed = 131072 */
#define OFF_WTMP   (OFF_WT + NE * DIM)        /* N_TOK*TOPK */

// pack 2 fp32 -> 2 truncated bf16 (hi) and 2 truncated bf16 of residual (lo)
__device__ inline void cvt2(float a, float b, unsigned& hi, unsigned& lo) {
    const unsigned ua = __float_as_uint(a), ub = __float_as_uint(b);
    hi = __builtin_amdgcn_perm(ub, ua, 0x07060302u);   // [a_hi16, b_hi16]
    const float ra = a - __uint_as_float(ua & 0xFFFF0000u);
    const float rb = b - __uint_as_float(ub & 0xFFFF0000u);
    lo = __builtin_amdgcn_perm(__float_as_uint(rb), __float_as_uint(ra), 0x07060302u);
}

union FragU { unsigned u[4]; bf16x8 v; uint4 q; };

__device__ inline void make_frags(const float4& p, const float4& q,
                                  bf16x8& hi, bf16x8& lo) {
    FragU H, L;
    cvt2(p.x, p.y, H.u[0], L.u[0]);
    cvt2(p.z, p.w, H.u[1], L.u[1]);
    cvt2(q.x, q.y, H.u[2], L.u[2]);
    cvt2(q.z, q.w, H.u[3], L.u[3]);
    hi = H.v; lo = L.v;
}

// W -> (wh, wl) split-bf16 + wt fp32 transpose [k][e]; also zero nflag.
__global__ __launch_bounds__(256)
void k_wc(const float* __restrict__ W, unsigned short* __restrict__ wh,
          unsigned short* __restrict__ wl, float* __restrict__ wt,
          int* __restrict__ nflag) {
    if (blockIdx.x == 0 && threadIdx.x == 0) nflag[0] = 0;
    const int i = (blockIdx.x * 256 + threadIdx.x) * 8;
    const int e = i >> 11, k = i & (DIM - 1);
    const float4 p = *reinterpret_cast<const float4*>(W + i);
    const float4 q = *reinterpret_cast<const float4*>(W + i + 4);
    FragU H, L;
    cvt2(p.x, p.y, H.u[0], L.u[0]);
    cvt2(p.z, p.w, H.u[1], L.u[1]);
    cvt2(q.x, q.y, H.u[2], L.u[2]);
    cvt2(q.z, q.w, H.u[3], L.u[3]);
    *reinterpret_cast<uint4*>(wh + i) = H.q;
    *reinterpret_cast<uint4*>(wl + i) = L.q;
    wt[(size_t)(k + 0) * NE + e] = p.x;
    wt[(size_t)(k + 1) * NE + e] = p.y;
    wt[(size_t)(k + 2) * NE + e] = p.z;
    wt[(size_t)(k + 3) * NE + e] = p.w;
    wt[(size_t)(k + 4) * NE + e] = q.x;
    wt[(size_t)(k + 5) * NE + e] = q.y;
    wt[(size_t)(k + 6) * NE + e] = q.z;
    wt[(size_t)(k + 7) * NE + e] = q.w;
}

// Fused split-bf16 MFMA GEMM + per-token stats. 512 thr (8 waves), 16 tokens,
// wave w owns k-chunk [w*256, w*256+256). 3 MFMA products (al*bl dropped:
// ~4e-6 << THETA/2). Two acc chains per N-tile for ILP; x and B-hi double-
// buffered, B-lo same-step (hidden behind the 8 hi-MFMAs).
__global__ __launch_bounds__(512, 4)
void k_main(const float* __restrict__ x, const unsigned short* __restrict__ wh,
            const unsigned short* __restrict__ wl, const float* __restrict__ bias,
            float* __restrict__ logits, float* __restrict__ maxv,
            float* __restrict__ denomv, float* __restrict__ w1f,
            int* __restrict__ c1, int* __restrict__ nflag, int* __restrict__ flagl) {
    __shared__ float red[8][TPB2][68];
    __shared__ float lbuf[TPB2][68];

    const int tid = threadIdx.x;
    const int w   = tid >> 6;
    const int l   = tid & 63;
    const int t0  = blockIdx.x * TPB2;
    const int m   = l & 15;
    const int g   = l >> 4;
    const int kb  = w * (DIM / 8);

    const float* xp = x + (size_t)(t0 + m) * DIM + kb + g * 8;
    const unsigned short* whp = wh + (size_t)m * DIM + kb + g * 8;
    const unsigned short* wlp = wl + (size_t)m * DIM + kb + g * 8;

    f32x4 accA[4], accB[4];
    #pragma unroll
    for (int nt = 0; nt < 4; ++nt)
        #pragma unroll
        for (int r = 0; r < 4; ++r) { accA[nt][r] = 0.0f; accB[nt][r] = 0.0f; }

    float4 P[2], Q[2];
    uint4  BH[2][4];
    P[0] = *reinterpret_cast<const float4*>(xp);
    Q[0] = *reinterpret_cast<const float4*>(xp + 4);
    #pragma unroll
    for (int nt = 0; nt < 4; ++nt)
        BH[0][nt] = *reinterpret_cast<const uint4*>(whp + (size_t)nt * 16 * DIM);

    #pragma unroll
    for (int step = 0; step < 8; ++step) {
        const int cur = step & 1, nxt = cur ^ 1;
        if (step < 7) {
            P[nxt] = *reinterpret_cast<const float4*>(xp + (step + 1) * 32);
            Q[nxt] = *reinterpret_cast<const float4*>(xp + (step + 1) * 32 + 4);
            #pragma unroll
            for (int nt = 0; nt < 4; ++nt)
                BH[nxt][nt] = *reinterpret_cast<const uint4*>(
                    whp + (size_t)nt * 16 * DIM + (step + 1) * 32);
        }
        uint4 BL[4];
        #pragma unroll
        for (int nt = 0; nt < 4; ++nt)
            BL[nt] = *reinterpret_cast<const uint4*>(
                wlp + (size_t)nt * 16 * DIM + step * 32);

        bf16x8 ah, al;
        make_frags(P[cur], Q[cur], ah, al);

        #pragma unroll
        for (int nt = 0; nt < 4; ++nt) {
            FragU bh; bh.q = BH[cur][nt];
            accA[nt] = __builtin_amdgcn_mfma_f32_16x16x32_bf16(ah, bh.v, accA[nt], 0, 0, 0);
            accB[nt] = __builtin_amdgcn_mfma_f32_16x16x32_bf16(al, bh.v, accB[nt], 0, 0, 0);
        }
        #pragma unroll
        for (int nt = 0; nt < 4; ++nt) {
            FragU bl; bl.q = BL[nt];
            accB[nt] = __builtin_amdgcn_mfma_f32_16x16x32_bf16(ah, bl.v, accB[nt], 0, 0, 0);
        }
    }

    #pragma unroll
    for (int nt = 0; nt < 4; ++nt)
        #pragma unroll
        for (int r = 0; r < 4; ++r)
            red[w][g * 4 + r][nt * 16 + m] = accA[nt][r] + accB[nt][r];
    __syncthreads();

    for (int e2 = tid; e2 < TPB2 * NE; e2 += 512) {
        const int t = e2 >> 6, e = e2 & 63;
        float s = red[0][t][e];
        #pragma unroll
        for (int ww = 1; ww < 8; ++ww) s += red[ww][t][e];
        s += bias[e];
        logits[(size_t)(t0 + t) * NE + e] = s;
        lbuf[t][e] = s;
    }
    __syncthreads();

    #pragma unroll
    for (int tt = 0; tt < 2; ++tt) {
        const int t = w * 2 + tt;
        const float lv = lbuf[t][l];
        float v1 = lv; int i1 = l; float v2 = -INFINITY;
        #pragma unroll
        for (int off = 32; off; off >>= 1) {
            const float ov1 = __shfl_xor(v1, off);
            const int   oi1 = __shfl_xor(i1, off);
            const float ov2 = __shfl_xor(v2, off);
            if (ov1 > v1 || (ov1 == v1 && oi1 < i1)) {
                v2 = fmaxf(v1, ov2); v1 = ov1; i1 = oi1;
            } else {
                v2 = fmaxf(v2, ov1);
            }
        }
        float s = expf(lv - v1);
        #pragma unroll
        for (int off = 32; off; off >>= 1) s += __shfl_xor(s, off);
        if (l == 0) {
            const int row = t0 + t;
            maxv[row]   = v1;
            denomv[row] = s;
            c1[row]     = i1;
            w1f[row]    = 1.0f / s;
            if (v1 - v2 < THETA) {
                const int ix = atomicAdd(nflag, 1);
                flagl[ix] = row;
            }
        }
    }
}

// Exact fp32 recompute for gap-flagged tokens. Reads wt [k][e] (coalesced,
// lane = expert); fmaf sequence identical to rounds 1-3 (per-512 strip,
// sequential k, then bias + strip0..3).
__global__ __launch_bounds__(256)
void k_exact(const int* __restrict__ nflag, const int* __restrict__ flagl,
             const float* __restrict__ x, const float* __restrict__ wt,
             const float* __restrict__ bias, float* __restrict__ logits,
             float* __restrict__ maxv, float* __restrict__ denomv,
             float* __restrict__ w1f, int* __restrict__ c1) {
    __shared__ float part[4][68];
    const int n   = nflag[0];
    const int tid = threadIdx.x;
    const int w   = tid >> 6, l = tid & 63;
    for (int i = blockIdx.x; i < n; i += 128) {
        const int t = flagl[i];
        const float* xr = x + (size_t)t * DIM + w * 512;
        const float* wb = wt + (size_t)(w * 512) * NE + l;
        float a = 0.0f;
        for (int k = 0; k < 512; k += 4) {
            const float4 xv = *reinterpret_cast<const float4*>(xr + k);
            a = fmaf(xv.x, wb[(size_t)(k + 0) * NE], a);
            a = fmaf(xv.y, wb[(size_t)(k + 1) * NE], a);
            a = fmaf(xv.z, wb[(size_t)(k + 2) * NE], a);
            a = fmaf(xv.w, wb[(size_t)(k + 3) * NE], a);
        }
        part[w][l] = a;
        __syncthreads();
        if (w == 0) {
            float lg = bias[l];
            #pragma unroll
            for (int s = 0; s < 4; ++s) lg += part[s][l];
            logits[(size_t)t * NE + l] = lg;
            float v = lg; int idx = l;
            #pragma unroll
            for (int off = 32; off; off >>= 1) {
                const float ov = __shfl_xor(v, off);
                const int   oi = __shfl_xor(idx, off);
                if (ov > v || (ov == v && oi < idx)) { v = ov; idx = oi; }
            }
            float p = expf(lg - v);
            #pragma unroll
            for (int off = 32; off; off >>= 1) p += __shfl_xor(p, off);
            if (l == 0) {
                maxv[t]   = v;
                denomv[t] = p;
                c1[t]     = idx;
                w1f[t]    = 1.0f / p;
            }
        }
        __syncthreads();
    }
}

// histogram -> capacity flag -> fast write or exact serial fallback
__global__ __launch_bounds__(256)
void k_decide(const int* __restrict__ c1, const float* __restrict__ w1,
              const float* __restrict__ logits, const float* __restrict__ maxv,
              const float* __restrict__ denomv, const int* __restrict__ tc,
              float* __restrict__ out, float* __restrict__ wtmp) {
    __shared__ int hist[NE];
    __shared__ int flagS;
    const int tid = threadIdx.x;
    if (tid < NE) hist[tid] = 0;
    __syncthreads();
    for (int i = tid; i < N_TOK; i += 256) atomicAdd(&hist[c1[i]], 1);
    __syncthreads();
    const int cap = tc[0] / TOPK;
    if (tid < NE) {
        const bool bad = (TOPK * hist[tid] > cap);
        const unsigned long long mm = __ballot(bad);
        if (tid == 0) flagS = (mm == 0ull) ? 1 : 0;
    }
    __syncthreads();

    if (flagS) {
        const int b = blockIdx.x * 256 + tid;
        const float se = (float)c1[b];
        const float wv = w1[b];
        const float wn = wv / (4.0f * wv + 1e-8f);
        *reinterpret_cast<float4*>(out + (size_t)b * 4) = make_float4(se, se, se, se);
        *reinterpret_cast<float4*>(out + (size_t)N_TOK * TOPK + (size_t)b * 4) =
            make_float4(wn, wn, wn, wn);
        return;
    }

    if (blockIdx.x != 0) return;
    if (tid < 64) {
        const int e = tid;
        int rem = cap;
        for (int k = 0; k < TOPK; ++k) {
            for (int b = 0; b < N_TOK; ++b) {
                const float lg = logits[(size_t)b * NE + e];
                float v = (rem > 0) ? lg : -INFINITY;
                int idx = e;
                #pragma unroll
                for (int off = 32; off; off >>= 1) {
                    const float ov = __shfl_xor(v, off);
                    const int   oi = __shfl_xor(idx, off);
                    if (ov > v || (ov == v && oi < idx)) { v = ov; idx = oi; }
                }
                const bool ok = (v != -INFINITY);
                if (ok && e == idx) rem -= 1;
                const float lc = __shfl(lg, idx);
                if (e == 0) {
                    out[(size_t)b * TOPK + k]  = ok ? (float)idx : -1.0f;
                    wtmp[(size_t)b * TOPK + k] = ok ? expf(lc - maxv[b]) / denomv[b] : 0.0f;
                }
            }
        }
    }
    __syncthreads();
    for (int b = tid; b < N_TOK; b += 256) {
        const float w0 = wtmp[b * 4 + 0], w1_ = wtmp[b * 4 + 1];
        const float w2 = wtmp[b * 4 + 2], w3 = wtmp[b * 4 + 3];
        const float s = ((w0 + w1_) + w2) + w3 + 1e-8f;
        out[N_TOK * TOPK + b * 4 + 0] = w0 / s;
        out[N_TOK * TOPK + b * 4 + 1] = w1_ / s;
        out[N_TOK * TOPK + b * 4 + 2] = w2 / s;
        out[N_TOK * TOPK + b * 4 + 3] = w3 / s;
    }
}

extern "C" void kernel_launch(void* const* d_in, const int* in_sizes, int n_in,
                              void* d_out, int out_size, void* d_ws, size_t ws_size,
                              hipStream_t stream) {
    const float* x    = (const float*)d_in[0];
    const float* W    = (const float*)d_in[1];
    const float* bias = (const float*)d_in[2];
    const int*   tc   = (const int*)d_in[3];

    float* ws       = (float*)d_ws;
    float* logits   = ws + OFF_LOGITS;
    float* maxv     = ws + OFF_MAXV;
    float* denomv   = ws + OFF_DENOM;
    float* w1f      = ws + OFF_W1;
    int*   c1       = (int*)(ws + OFF_C1);
    int*   nflag    = (int*)(ws + OFF_NFLAG);
    int*   flagl    = (int*)(ws + OFF_FLAGL);
    unsigned short* wh = (unsigned short*)(ws + OFF_WH);
    unsigned short* wl = (unsigned short*)(ws + OFF_WL);
    float* wt       = ws + OFF_WT;
    float* wtmp     = ws + OFF_WTMP;
    float* out      = (float*)d_out;

    k_wc<<<NE * DIM / 8 / 256, 256, 0, stream>>>(W, wh, wl, wt, nflag);
    k_main<<<NBLK, 512, 0, stream>>>(x, wh, wl, bias, logits, maxv, denomv,
                                     w1f, c1, nflag, flagl);
    k_exact<<<128, 256, 0, stream>>>(nflag, flagl, x, wt, bias, logits,
                                     maxv, denomv, w1f, c1);
    k_decide<<<N_TOK / 256, 256, 0, stream>>>(c1, w1f, logits, maxv, denomv,
                                              tc, out, wtmp);
}

// Round 5
// 131.755 us; speedup vs baseline: 1.2564x; 1.1761x over previous
//
#include <hip/hip_runtime.h>
#include <math.h>

#define N_TOK 8192
#define DIM   2048
#define NE    64
#define TOPK  4
#define THETA 2e-3f
#define TPB2  16                      /* tokens per k_main block */
#define NBLK  (N_TOK / TPB2)          /* 512 */
#define RSTR  260                     /* padded LDS row stride (floats) */

typedef short bf16x8 __attribute__((ext_vector_type(8)));
typedef float f32x4  __attribute__((ext_vector_type(4)));

// ---- workspace layout (float offsets) ----
#define OFF_LOGITS 0                          /* N_TOK*NE = 524288 */
#define OFF_MAXV   (OFF_LOGITS + N_TOK * NE)
#define OFF_DENOM  (OFF_MAXV + N_TOK)
#define OFF_W1     (OFF_DENOM + N_TOK)
#define OFF_C1     (OFF_W1 + N_TOK)           /* int */
#define OFF_NFLAG  (OFF_C1 + N_TOK)           /* int (padded 64) */
#define OFF_FLAGL  (OFF_NFLAG + 64)           /* int, N_TOK */
#define OFF_WH     (OFF_FLAGL + N_TOK)        /* NE*DIM bf16, frag-packed */
#define OFF_WL     (OFF_WH + NE * DIM / 2)
#define OFF_WT     (OFF_WL + NE * DIM / 2)    /* NE*DIM fp32 transposed */
#define OFF_WTMP   (OFF_WT + NE * DIM)        /* N_TOK*TOPK */

// pack 2 fp32 -> 2 truncated bf16 (hi) and 2 truncated bf16 of residual (lo)
__device__ inline void cvt2(float a, float b, unsigned& hi, unsigned& lo) {
    const unsigned ua = __float_as_uint(a), ub = __float_as_uint(b);
    hi = __builtin_amdgcn_perm(ub, ua, 0x07060302u);   // [a_hi16, b_hi16]
    const float ra = a - __uint_as_float(ua & 0xFFFF0000u);
    const float rb = b - __uint_as_float(ub & 0xFFFF0000u);
    lo = __builtin_amdgcn_perm(__float_as_uint(rb), __float_as_uint(ra), 0x07060302u);
}

union FragU { unsigned u[4]; bf16x8 v; uint4 q; };

__device__ inline void make_frags(const float4& p, const float4& q,
                                  bf16x8& hi, bf16x8& lo) {
    FragU H, L;
    cvt2(p.x, p.y, H.u[0], L.u[0]);
    cvt2(p.z, p.w, H.u[1], L.u[1]);
    cvt2(q.x, q.y, H.u[2], L.u[2]);
    cvt2(q.z, q.w, H.u[3], L.u[3]);
    hi = H.v; lo = L.v;
}

// W -> frag-packed (wh2, wl2): element for (kc, nt, lane, j) is
// W[e = nt*16 + (lane&15)][k = kc*32 + (lane>>4)*8 + j], stored at
// elem offset (kc*4+nt)*512 + lane*8 + j  -> B loads are contiguous 1KB/wave.
// Also wt fp32 transpose [k][e] for k_exact, and nflag zero.
__global__ __launch_bounds__(256)
void k_wc(const float* __restrict__ W, unsigned short* __restrict__ wh2,
          unsigned short* __restrict__ wl2, float* __restrict__ wt,
          int* __restrict__ nflag) {
    const int t = blockIdx.x * 256 + threadIdx.x;     // 0..16383
    if (t == 0) nflag[0] = 0;
    const int l  = t & 63;
    const int grp = t >> 6;                           // = kc*4 + nt, 0..255
    const int nt = grp & 3;
    const int kc = grp >> 2;
    const int e  = nt * 16 + (l & 15);
    const int k0 = kc * 32 + (l >> 4) * 8;

    const float4 p = *reinterpret_cast<const float4*>(W + (size_t)e * DIM + k0);
    const float4 q = *reinterpret_cast<const float4*>(W + (size_t)e * DIM + k0 + 4);
    FragU H, L;
    cvt2(p.x, p.y, H.u[0], L.u[0]);
    cvt2(p.z, p.w, H.u[1], L.u[1]);
    cvt2(q.x, q.y, H.u[2], L.u[2]);
    cvt2(q.z, q.w, H.u[3], L.u[3]);
    const size_t off = (size_t)grp * 512 + l * 8;
    *reinterpret_cast<uint4*>(wh2 + off) = H.q;
    *reinterpret_cast<uint4*>(wl2 + off) = L.q;

    wt[(size_t)(k0 + 0) * NE + e] = p.x;
    wt[(size_t)(k0 + 1) * NE + e] = p.y;
    wt[(size_t)(k0 + 2) * NE + e] = p.z;
    wt[(size_t)(k0 + 3) * NE + e] = p.w;
    wt[(size_t)(k0 + 4) * NE + e] = q.x;
    wt[(size_t)(k0 + 5) * NE + e] = q.y;
    wt[(size_t)(k0 + 6) * NE + e] = q.z;
    wt[(size_t)(k0 + 7) * NE + e] = q.w;
}

// Fused split-bf16 MFMA GEMM + stats. 512 thr (8 waves), 16 tokens.
// Window = 256 k staged in LDS (double-buffered); wave w consumes k-chunk
// win*256 + w*32. B from frag-packed global (contiguous 1KB loads, L2-hot).
// 3 MFMA products (al*bl dropped, ~4e-6 << THETA/2).
__global__ __launch_bounds__(512, 4)
void k_main(const float* __restrict__ x, const unsigned short* __restrict__ wh2,
            const unsigned short* __restrict__ wl2, const float* __restrict__ bias,
            float* __restrict__ logits, float* __restrict__ maxv,
            float* __restrict__ denomv, float* __restrict__ w1f,
            int* __restrict__ c1, int* __restrict__ nflag, int* __restrict__ flagl) {
    __shared__ __align__(16) float xs[2][TPB2 * RSTR];   // 33280 B
    __shared__ float red[8][TPB2][68];                    // 34816 B
    __shared__ float lbuf[TPB2][68];                      //  4352 B

    const int tid = threadIdx.x;
    const int w   = tid >> 6;            // wave 0..7
    const int l   = tid & 63;
    const int t0  = blockIdx.x * TPB2;
    const int m   = l & 15;              // token (A) / expert-low (B)
    const int g   = l >> 4;              // k-octet group

    // staging: wave w owns token rows 2w, 2w+1; lane covers 16B of the row
    const float* xrow0 = x + (size_t)(t0 + 2 * w) * DIM + l * 4;
    const float* xrow1 = x + (size_t)(t0 + 2 * w + 1) * DIM + l * 4;
    float* st0 = &xs[0][(2 * w) * RSTR + l * 4];
    float* st1 = &xs[0][(2 * w + 1) * RSTR + l * 4];
    const int xs1off = TPB2 * RSTR;      // xs[1] - xs[0]

    // B: elem offset (kc*4+nt)*512 + l*8, kc = win*8 + w
    const unsigned short* bh = wh2 + (size_t)w * 2048 + l * 8;
    const unsigned short* bl = wl2 + (size_t)w * 2048 + l * 8;

    f32x4 accA[4], accB[4];
    #pragma unroll
    for (int nt = 0; nt < 4; ++nt)
        #pragma unroll
        for (int r = 0; r < 4; ++r) { accA[nt][r] = 0.0f; accB[nt][r] = 0.0f; }

    // prologue: stage window 0, preload B window 0
    {
        const float4 r0 = *reinterpret_cast<const float4*>(xrow0);
        const float4 r1 = *reinterpret_cast<const float4*>(xrow1);
        *reinterpret_cast<float4*>(st0) = r0;
        *reinterpret_cast<float4*>(st1) = r1;
    }
    uint4 BH[2][4], BL[2][4];
    #pragma unroll
    for (int nt = 0; nt < 4; ++nt) {
        BH[0][nt] = *reinterpret_cast<const uint4*>(bh + nt * 512);
        BL[0][nt] = *reinterpret_cast<const uint4*>(bl + nt * 512);
    }
    __syncthreads();

    const int aoff = m * RSTR + w * 32 + g * 8;   // A frag base in window

    #pragma unroll
    for (int win = 0; win < 8; ++win) {
        const int cur = win & 1, nxt = cur ^ 1;
        float4 nx0, nx1;
        if (win < 7) {
            nx0 = *reinterpret_cast<const float4*>(xrow0 + (win + 1) * 256);
            nx1 = *reinterpret_cast<const float4*>(xrow1 + (win + 1) * 256);
            #pragma unroll
            for (int nt = 0; nt < 4; ++nt) {
                BH[nxt][nt] = *reinterpret_cast<const uint4*>(
                    bh + (size_t)(win + 1) * 16384 + nt * 512);
                BL[nxt][nt] = *reinterpret_cast<const uint4*>(
                    bl + (size_t)(win + 1) * 16384 + nt * 512);
            }
        }

        const float4 p = *reinterpret_cast<const float4*>(&xs[0][cur * xs1off + aoff]);
        const float4 q = *reinterpret_cast<const float4*>(&xs[0][cur * xs1off + aoff + 4]);
        bf16x8 ah, al;
        make_frags(p, q, ah, al);

        #pragma unroll
        for (int nt = 0; nt < 4; ++nt) {
            FragU b; b.q = BH[cur][nt];
            accA[nt] = __builtin_amdgcn_mfma_f32_16x16x32_bf16(ah, b.v, accA[nt], 0, 0, 0);
            accB[nt] = __builtin_amdgcn_mfma_f32_16x16x32_bf16(al, b.v, accB[nt], 0, 0, 0);
        }
        #pragma unroll
        for (int nt = 0; nt < 4; ++nt) {
            FragU b; b.q = BL[cur][nt];
            accB[nt] = __builtin_amdgcn_mfma_f32_16x16x32_bf16(ah, b.v, accB[nt], 0, 0, 0);
        }

        if (win < 7) {
            *reinterpret_cast<float4*>(st0 + nxt * xs1off) = nx0;
            *reinterpret_cast<float4*>(st1 + nxt * xs1off) = nx1;
        }
        __syncthreads();
    }

    #pragma unroll
    for (int nt = 0; nt < 4; ++nt)
        #pragma unroll
        for (int r = 0; r < 4; ++r)
            red[w][g * 4 + r][nt * 16 + m] = accA[nt][r] + accB[nt][r];
    __syncthreads();

    for (int e2 = tid; e2 < TPB2 * NE; e2 += 512) {
        const int t = e2 >> 6, e = e2 & 63;
        float s = red[0][t][e];
        #pragma unroll
        for (int ww = 1; ww < 8; ++ww) s += red[ww][t][e];
        s += bias[e];
        logits[(size_t)(t0 + t) * NE + e] = s;
        lbuf[t][e] = s;
    }
    __syncthreads();

    #pragma unroll
    for (int tt = 0; tt < 2; ++tt) {
        const int t = w * 2 + tt;
        const float lv = lbuf[t][l];
        float v1 = lv; int i1 = l; float v2 = -INFINITY;
        #pragma unroll
        for (int off = 32; off; off >>= 1) {
            const float ov1 = __shfl_xor(v1, off);
            const int   oi1 = __shfl_xor(i1, off);
            const float ov2 = __shfl_xor(v2, off);
            if (ov1 > v1 || (ov1 == v1 && oi1 < i1)) {
                v2 = fmaxf(v1, ov2); v1 = ov1; i1 = oi1;
            } else {
                v2 = fmaxf(v2, ov1);
            }
        }
        float s = expf(lv - v1);
        #pragma unroll
        for (int off = 32; off; off >>= 1) s += __shfl_xor(s, off);
        if (l == 0) {
            const int row = t0 + t;
            maxv[row]   = v1;
            denomv[row] = s;
            c1[row]     = i1;
            w1f[row]    = 1.0f / s;
            if (v1 - v2 < THETA) {
                const int ix = atomicAdd(nflag, 1);
                flagl[ix] = row;
            }
        }
    }
}

// Exact fp32 recompute for gap-flagged tokens (coalesced wt [k][e] reads).
__global__ __launch_bounds__(256)
void k_exact(const int* __restrict__ nflag, const int* __restrict__ flagl,
             const float* __restrict__ x, const float* __restrict__ wt,
             const float* __restrict__ bias, float* __restrict__ logits,
             float* __restrict__ maxv, float* __restrict__ denomv,
             float* __restrict__ w1f, int* __restrict__ c1) {
    __shared__ float part[4][68];
    const int n   = nflag[0];
    const int tid = threadIdx.x;
    const int w   = tid >> 6, l = tid & 63;
    for (int i = blockIdx.x; i < n; i += 64) {
        const int t = flagl[i];
        const float* xr = x + (size_t)t * DIM + w * 512;
        const float* wb = wt + (size_t)(w * 512) * NE + l;
        float a = 0.0f;
        for (int k = 0; k < 512; k += 4) {
            const float4 xv = *reinterpret_cast<const float4*>(xr + k);
            a = fmaf(xv.x, wb[(size_t)(k + 0) * NE], a);
            a = fmaf(xv.y, wb[(size_t)(k + 1) * NE], a);
            a = fmaf(xv.z, wb[(size_t)(k + 2) * NE], a);
            a = fmaf(xv.w, wb[(size_t)(k + 3) * NE], a);
        }
        part[w][l] = a;
        __syncthreads();
        if (w == 0) {
            float lg = bias[l];
            #pragma unroll
            for (int s = 0; s < 4; ++s) lg += part[s][l];
            logits[(size_t)t * NE + l] = lg;
            float v = lg; int idx = l;
            #pragma unroll
            for (int off = 32; off; off >>= 1) {
                const float ov = __shfl_xor(v, off);
                const int   oi = __shfl_xor(idx, off);
                if (ov > v || (ov == v && oi < idx)) { v = ov; idx = oi; }
            }
            float p = expf(lg - v);
            #pragma unroll
            for (int off = 32; off; off >>= 1) p += __shfl_xor(p, off);
            if (l == 0) {
                maxv[t]   = v;
                denomv[t] = p;
                c1[t]     = idx;
                w1f[t]    = 1.0f / p;
            }
        }
        __syncthreads();
    }
}

// histogram -> capacity flag -> fast write or exact serial fallback
__global__ __launch_bounds__(256)
void k_decide(const int* __restrict__ c1, const float* __restrict__ w1,
              const float* __restrict__ logits, const float* __restrict__ maxv,
              const float* __restrict__ denomv, const int* __restrict__ tc,
              float* __restrict__ out, float* __restrict__ wtmp) {
    __shared__ int hist[NE];
    __shared__ int flagS;
    const int tid = threadIdx.x;
    if (tid < NE) hist[tid] = 0;
    __syncthreads();
    for (int i = tid; i < N_TOK; i += 256) atomicAdd(&hist[c1[i]], 1);
    __syncthreads();
    const int cap = tc[0] / TOPK;
    if (tid < NE) {
        const bool bad = (TOPK * hist[tid] > cap);
        const unsigned long long mm = __ballot(bad);
        if (tid == 0) flagS = (mm == 0ull) ? 1 : 0;
    }
    __syncthreads();

    if (flagS) {
        const int b = blockIdx.x * 256 + tid;
        const float se = (float)c1[b];
        const float wv = w1[b];
        const float wn = wv / (4.0f * wv + 1e-8f);
        *reinterpret_cast<float4*>(out + (size_t)b * 4) = make_float4(se, se, se, se);
        *reinterpret_cast<float4*>(out + (size_t)N_TOK * TOPK + (size_t)b * 4) =
            make_float4(wn, wn, wn, wn);
        return;
    }

    if (blockIdx.x != 0) return;
    if (tid < 64) {
        const int e = tid;
        int rem = cap;
        for (int k = 0; k < TOPK; ++k) {
            for (int b = 0; b < N_TOK; ++b) {
                const float lg = logits[(size_t)b * NE + e];
                float v = (rem > 0) ? lg : -INFINITY;
                int idx = e;
                #pragma unroll
                for (int off = 32; off; off >>= 1) {
                    const float ov = __shfl_xor(v, off);
                    const int   oi = __shfl_xor(idx, off);
                    if (ov > v || (ov == v && oi < idx)) { v = ov; idx = oi; }
                }
                const bool ok = (v != -INFINITY);
                if (ok && e == idx) rem -= 1;
                const float lc = __shfl(lg, idx);
                if (e == 0) {
                    out[(size_t)b * TOPK + k]  = ok ? (float)idx : -1.0f;
                    wtmp[(size_t)b * TOPK + k] = ok ? expf(lc - maxv[b]) / denomv[b] : 0.0f;
                }
            }
        }
    }
    __syncthreads();
    for (int b = tid; b < N_TOK; b += 256) {
        const float w0 = wtmp[b * 4 + 0], w1_ = wtmp[b * 4 + 1];
        const float w2 = wtmp[b * 4 + 2], w3 = wtmp[b * 4 + 3];
        const float s = ((w0 + w1_) + w2) + w3 + 1e-8f;
        out[N_TOK * TOPK + b * 4 + 0] = w0 / s;
        out[N_TOK * TOPK + b * 4 + 1] = w1_ / s;
        out[N_TOK * TOPK + b * 4 + 2] = w2 / s;
        out[N_TOK * TOPK + b * 4 + 3] = w3 / s;
    }
}

extern "C" void kernel_launch(void* const* d_in, const int* in_sizes, int n_in,
                              void* d_out, int out_size, void* d_ws, size_t ws_size,
                              hipStream_t stream) {
    const float* x    = (const float*)d_in[0];
    const float* W    = (const float*)d_in[1];
    const float* bias = (const float*)d_in[2];
    const int*   tc   = (const int*)d_in[3];

    float* ws       = (float*)d_ws;
    float* logits   = ws + OFF_LOGITS;
    float* maxv     = ws + OFF_MAXV;
    float* denomv   = ws + OFF_DENOM;
    float* w1f      = ws + OFF_W1;
    int*   c1       = (int*)(ws + OFF_C1);
    int*   nflag    = (int*)(ws + OFF_NFLAG);
    int*   flagl    = (int*)(ws + OFF_FLAGL);
    unsigned short* wh2 = (unsigned short*)(ws + OFF_WH);
    unsigned short* wl2 = (unsigned short*)(ws + OFF_WL);
    float* wt       = ws + OFF_WT;
    float* wtmp     = ws + OFF_WTMP;
    float* out      = (float*)d_out;

    k_wc<<<NE * DIM / 8 / 256, 256, 0, stream>>>(W, wh2, wl2, wt, nflag);
    k_main<<<NBLK, 512, 0, stream>>>(x, wh2, wl2, bias, logits, maxv, denomv,
                                     w1f, c1, nflag, flagl);
    k_exact<<<64, 256, 0, stream>>>(nflag, flagl, x, wt, bias, logits,
                                    maxv, denomv, w1f, c1);
    k_decide<<<N_TOK / 256, 256, 0, stream>>>(c1, w1f, logits, maxv, denomv,
                                              tc, out, wtmp);
}